// Round 17
// baseline (732.952 us; speedup 1.0000x reference)
//
#include <hip/hip_runtime.h>
#include <math.h>

#define T_LEN    480000
#define NB       8
#define NK       157      // chunks per batch
#define CHUNKSZ  4096
#define STRIDESZ 3072
#define NFFT_SZ  1024
#define HOP_SZ   256
#define NFREQ    513
#define NFR      13       // frames per chunk
#define HDIM     256
#define EDIM     128
#define GDIM     768      // 3*HDIM
#define PDIM     1026     // 2*NFREQ
#define FR_STRIDE 1026    // bf16 shorts per frame slot in spec buffer (513 uints)
#define NFRAMES  (NB*NK*NFR)   // 16328
#define NCHUNKS  (NB*NK)       // 1256
#define KCF      2041          // NK*NFR, frames per batch

// xg-GEMM tiling
#define XG_KS    17            // K-steps of 32 (K padded 516 -> 544)
#define XG_NB    3             // N blocks of 256 (768 total)
// proj-GEMM tiling
#define PJ_KS    8             // K = 256
#define PJ_NB    5             // N blocks of 256 (1026 -> 1280 padded)
// GRU: 1024 threads, split-K x4, weights resident in VGPRs (48 float4/thread)
#define GRU_CT   5

#define TWO_PI_D 6.283185307179586

typedef short bf16x8 __attribute__((ext_vector_type(8)));
typedef float f32x4  __attribute__((ext_vector_type(4)));

__device__ __forceinline__ void split_bf16(float v, short& hi, short& lo) {
  unsigned u = __float_as_uint(v);
  hi = (short)(u >> 16);
  float fh = __uint_as_float(u & 0xFFFF0000u);
  float res = v - fh;
  lo = (short)(__float_as_uint(res) >> 16);
}

__device__ __forceinline__ unsigned short f2bf(float v) {   // round-to-nearest-even
  unsigned u = __float_as_uint(v);
  u += 0x7FFFu + ((u >> 16) & 1u);
  return (unsigned short)(u >> 16);
}
__device__ __forceinline__ float bf2f(unsigned short b) {
  return __uint_as_float(((unsigned)b) << 16);
}

// ---------------- 512-pt complex FFT x 2 frames, fused stage pairs ----------------
__device__ __forceinline__ void fft512x2(float (*re)[512], float (*im)[512],
                                         const float* twc, const float* tws,
                                         int tid, float dir) {
  int q = tid >> 7;        // frame
  int j = tid & 127;       // quad id (128 quads per frame)
  #pragma unroll
  for (int s = 1; s <= 7; s += 2) {
    int half = 1 << (s - 1);            // 1,4,16,64
    int p   = j & (half - 1);
    int grp = j >> (s - 1);
    int i0  = grp * 4 * half + p;
    int i1  = i0 + half;
    int i2  = i0 + 2 * half;
    int i3  = i0 + 3 * half;
    float r0 = re[q][i0], q0 = im[q][i0], r1 = re[q][i1], q1 = im[q][i1];
    float r2 = re[q][i2], q2 = im[q][i2], r3 = re[q][i3], q3 = im[q][i3];
    int qa = p << (10 - s);
    float ca = twc[qa], sa = dir * tws[qa];
    float tr = ca * r1 - sa * q1, ti = ca * q1 + sa * r1;
    float u0r = r0 + tr, u0i = q0 + ti;
    float u1r = r0 - tr, u1i = q0 - ti;
    tr = ca * r3 - sa * q3; ti = ca * q3 + sa * r3;
    float u2r = r2 + tr, u2i = q2 + ti;
    float u3r = r2 - tr, u3i = q2 - ti;
    int qb = p << (9 - s);
    int qc = (p + half) << (9 - s);
    float cb = twc[qb], sb = dir * tws[qb];
    float cc = twc[qc], sc = dir * tws[qc];
    tr = cb * u2r - sb * u2i; ti = cb * u2i + sb * u2r;
    re[q][i0] = u0r + tr; im[q][i0] = u0i + ti;
    re[q][i2] = u0r - tr; im[q][i2] = u0i - ti;
    tr = cc * u3r - sc * u3i; ti = cc * u3i + sc * u3r;
    re[q][i1] = u1r + tr; im[q][i1] = u1i + ti;
    re[q][i3] = u1r - tr; im[q][i3] = u1i - ti;
    __syncthreads();
  }
  {
    int p = tid;           // 0..255
    int qd = p << 1;       // e^{-2pi i p/512}
    float c = twc[qd], sn = dir * tws[qd];
    #pragma unroll
    for (int f = 0; f < 2; ++f) {
      int i1 = p, i2 = p + 256;
      float r2 = re[f][i2], q2 = im[f][i2];
      float tr = c * r2 - sn * q2;
      float ti = c * q2 + sn * r2;
      float r1 = re[f][i1], q1 = im[f][i1];
      re[f][i2] = r1 - tr; im[f][i2] = q1 - ti;
      re[f][i1] = r1 + tr; im[f][i1] = q1 + ti;
    }
    __syncthreads();
  }
}

// ---------------- window + 1/wsum + twiddle tables (recomputed every call) ----------------
__global__ void k_tables(float* __restrict__ win, float* __restrict__ wsinv,
                         float* __restrict__ twc, float* __restrict__ tws) {
  int tid = threadIdx.x;
  for (int i = tid; i < NFFT_SZ; i += 256) {
    double w = 0.5 - 0.5 * cos((TWO_PI_D / (double)NFFT_SZ) * (double)i);
    win[i] = (float)w;
  }
  for (int i = tid; i < 512; i += 256) {
    double th = (TWO_PI_D / (double)NFFT_SZ) * (double)i;
    twc[i] = (float)cos(th);
    tws[i] = (float)sin(th);
  }
  for (int pc = tid; pc < CHUNKSZ; pc += 256) {
    int t1 = min(NFR - 1, pc >> 8);
    int t0 = (pc > NFFT_SZ - 1) ? ((pc - 768) >> 8) : 0;
    float ws = 0.f;
    for (int tt = t0; tt <= t1; ++tt) {
      int n = pc - tt * HOP_SZ;
      double w = 0.5 - 0.5 * cos((TWO_PI_D / (double)NFFT_SZ) * (double)n);
      float wf = (float)w;
      ws += wf * wf;
    }
    wsinv[pc] = 1.0f / fmaxf(ws, 1e-8f);
  }
}

// ---------------- one-time wx transpose+split into blocked bf16 hi/lo ----------------
__global__ void k_prep(const float* __restrict__ wx,
                       short* __restrict__ wxb_hi, short* __restrict__ wxb_lo) {
  int id = blockIdx.x * 256 + threadIdx.x;
  if (id >= XG_NB * XG_KS * 256) return;
  int nb  = id / (XG_KS * 256);
  int ks  = (id / 256) % XG_KS;
  int col = id % 256;
  int col_g = nb * 256 + col;
  size_t base = (size_t)id * 32;
  for (int j = 0; j < 32; ++j) {
    int k_g = ks * 32 + j;
    float v = wx[(size_t)k_g * GDIM + col_g];
    short hi, lo;
    split_bf16(v, hi, lo);
    wxb_hi[base + j] = hi;
    wxb_lo[base + j] = lo;
  }
}

// ---------------- wh transpose: whT4[k/4][col] = float4(wh[k..k+3][col]) ----------------
__global__ void k_prep_wht(const float* __restrict__ wh, float4* __restrict__ whT4) {
  int id = blockIdx.x * 256 + threadIdx.x;   // over 64*768 float4s
  if (id >= 64 * GDIM) return;
  int k4  = id / GDIM;
  int col = id % GDIM;
  whT4[id] = make_float4(wh[(size_t)(k4 * 4 + 0) * GDIM + col],
                         wh[(size_t)(k4 * 4 + 1) * GDIM + col],
                         wh[(size_t)(k4 * 4 + 2) * GDIM + col],
                         wh[(size_t)(k4 * 4 + 3) * GDIM + col]);
}

// ---------------- pw transpose+split: pwb[nb][ks][col][32] hi/lo ----------------
__global__ void k_prep_pw(const float* __restrict__ pw,
                          short* __restrict__ pwb_hi, short* __restrict__ pwb_lo) {
  int id = blockIdx.x * 256 + threadIdx.x;   // over 5*8*256
  if (id >= PJ_NB * PJ_KS * 256) return;
  int nb  = id / (PJ_KS * 256);
  int ks  = (id / 256) % PJ_KS;
  int col = id % 256;
  int col_g = nb * 256 + col;
  size_t base = (size_t)id * 32;
  for (int j = 0; j < 32; ++j) {
    int k_g = ks * 32 + j;
    float v = (col_g < PDIM) ? pw[(size_t)k_g * PDIM + col_g] : 0.f;
    short hi, lo;
    split_bf16(v, hi, lo);
    pwb_hi[base + j] = hi;
    pwb_lo[base + j] = lo;
  }
}

// ---------------- emb @ wx_emb precompute: embxg[b][col] ----------------
__global__ void k_embxg(const float* __restrict__ emb_table, const int* __restrict__ effect_id,
                        const float* __restrict__ wx, float* __restrict__ embxg) {
  int b = blockIdx.x;
  int tid = threadIdx.x;
  int e_id = effect_id[b];
  const float* ev = emb_table + (size_t)e_id * EDIM;
  #pragma unroll
  for (int j = 0; j < 3; ++j) {
    int col = tid + 256 * j;
    float acc = 0.f;
    #pragma unroll 4
    for (int e = 0; e < EDIM; ++e)
      acc += ev[e] * wx[(size_t)(NFREQ + e) * GDIM + col];
    embxg[(size_t)b * GDIM + col] = acc;
  }
}

// ---------------- forward STFT via real-split 512-pt FFT, 2 frames/block ----------------
__global__ void k_stft(const float* __restrict__ audio, const float* __restrict__ win,
                       const float* __restrict__ gtwc, const float* __restrict__ gtws,
                       unsigned* __restrict__ spec) {
  int fr0 = blockIdx.x * 2;
  int tid = threadIdx.x;
  __shared__ float xin[2][NFFT_SZ];              // 8 KB
  __shared__ float re[2][512], im[2][512];       // 8 KB
  __shared__ float twc[512], tws[512];           // 4 KB
  for (int i = tid; i < 512; i += 256) { twc[i] = gtwc[i]; tws[i] = gtws[i]; }
  for (int i = tid; i < 2 * NFFT_SZ; i += 256) {
    int q = i >> 10, ii = i & 1023;
    int fr = fr0 + q;
    int b   = fr / KCF;
    int rem = fr % KCF;
    int k = rem / NFR, t = rem % NFR;
    int pos = k * STRIDESZ + t * HOP_SZ + ii;
    float v = (pos < T_LEN) ? audio[b * T_LEN + pos] : 0.f;
    xin[q][ii] = v * win[ii];
  }
  __syncthreads();
  for (int i = tid; i < 1024; i += 256) {
    int q = i >> 9, n = i & 511;
    int rv = (int)(__brev((unsigned)n) >> 23);
    re[q][n] = xin[q][2 * rv];
    im[q][n] = xin[q][2 * rv + 1];
  }
  __syncthreads();
  fft512x2(re, im, twc, tws, tid, -1.f);
  for (int i = tid; i < 1024; i += 256) {
    int q = i >> 9, k = i & 511;
    int m = (512 - k) & 511;
    float zr = re[q][k],  zi = im[q][k];
    float mr = re[q][m],  mi = -im[q][m];        // conj(Z[m])
    float xer = 0.5f * (zr + mr), xei = 0.5f * (zi + mi);
    float dr  = 0.5f * (zr - mr), di  = 0.5f * (zi - mi);
    float xor_ = di, xoi = -dr;
    float c = twc[k], s = tws[k];
    float Xr = xer + c * xor_ + s * xoi;
    float Xi = xei + c * xoi - s * xor_;
    unsigned* sp = spec + (size_t)(fr0 + q) * (FR_STRIDE / 2);
    sp[k] = (((unsigned)f2bf(Xi)) << 16) | (unsigned)f2bf(Xr);
  }
  if (tid < 2) {
    int q = tid;
    float Xr = re[q][0] - im[q][0];
    unsigned* sp = spec + (size_t)(fr0 + q) * (FR_STRIDE / 2);
    sp[512] = (((unsigned)f2bf(0.f)) << 16) | (unsigned)f2bf(Xr);
  }
}

// ---------------- xg GEMM via MFMA bf16x3 split ----------------
__global__ __launch_bounds__(256) void k_xg(
    const unsigned* __restrict__ spec, const float* __restrict__ embxg,
    const short* __restrict__ wxb_hi, const short* __restrict__ wxb_lo,
    float* __restrict__ xg) {
  int nb  = blockIdx.x % XG_NB;
  int mb  = blockIdx.x / XG_NB;
  int fr0 = mb * 64;
  int tid = threadIdx.x;
  int lane = tid & 63;
  int wv   = tid >> 6;

  __shared__ __align__(16) short lsA[2][64 * 40];
  __shared__ __align__(16) short lsB[2][256 * 40];

  f32x4 acc[4][4];
  #pragma unroll
  for (int i = 0; i < 4; ++i)
    #pragma unroll
    for (int j = 0; j < 4; ++j)
      acc[i][j] = (f32x4){0.f, 0.f, 0.f, 0.f};

  int lrow = lane & 15;
  int lk8  = (lane >> 4) * 8;

  for (int ks = 0; ks < XG_KS; ++ks) {
    int k0 = ks * 32;
    {
      int f = tid >> 2, q = tid & 3;
      int fr = fr0 + f;
      short hi[8], lo[8];
      #pragma unroll
      for (int j = 0; j < 8; ++j) {
        int bg = k0 + q * 8 + j;
        float m = 0.f;
        if (fr < NFRAMES && bg <= 512) {
          unsigned pv = spec[(size_t)fr * (FR_STRIDE / 2) + bg];
          float rr = bf2f((unsigned short)(pv & 0xFFFFu));
          float ii = bf2f((unsigned short)(pv >> 16));
          m = sqrtf(rr * rr + ii * ii);
        }
        split_bf16(m, hi[j], lo[j]);
      }
      int off = f * 40 + q * 8;
      *(bf16x8*)&lsA[0][off] = *(bf16x8*)hi;
      *(bf16x8*)&lsA[1][off] = *(bf16x8*)lo;
    }
    {
      const short* gh = wxb_hi + (((size_t)nb * XG_KS + ks) * 256 + tid) * 32;
      const short* gl = wxb_lo + (((size_t)nb * XG_KS + ks) * 256 + tid) * 32;
      int off = tid * 40;
      #pragma unroll
      for (int i = 0; i < 4; ++i) {
        *(bf16x8*)&lsB[0][off + 8 * i] = *(const bf16x8*)(gh + 8 * i);
        *(bf16x8*)&lsB[1][off + 8 * i] = *(const bf16x8*)(gl + 8 * i);
      }
    }
    __syncthreads();
    bf16x8 aH[4], aL[4], bH[4], bL[4];
    #pragma unroll
    for (int mt = 0; mt < 4; ++mt) {
      int off = (16 * mt + lrow) * 40 + lk8;
      aH[mt] = *(const bf16x8*)&lsA[0][off];
      aL[mt] = *(const bf16x8*)&lsA[1][off];
    }
    #pragma unroll
    for (int nt = 0; nt < 4; ++nt) {
      int col = wv * 64 + nt * 16 + lrow;
      int off = col * 40 + lk8;
      bH[nt] = *(const bf16x8*)&lsB[0][off];
      bL[nt] = *(const bf16x8*)&lsB[1][off];
    }
    #pragma unroll
    for (int mt = 0; mt < 4; ++mt)
      #pragma unroll
      for (int nt = 0; nt < 4; ++nt) {
        acc[mt][nt] = __builtin_amdgcn_mfma_f32_16x16x32_bf16(aH[mt], bH[nt], acc[mt][nt], 0, 0, 0);
        acc[mt][nt] = __builtin_amdgcn_mfma_f32_16x16x32_bf16(aH[mt], bL[nt], acc[mt][nt], 0, 0, 0);
        acc[mt][nt] = __builtin_amdgcn_mfma_f32_16x16x32_bf16(aL[mt], bH[nt], acc[mt][nt], 0, 0, 0);
      }
    __syncthreads();
  }

  int ncol0 = nb * 256 + wv * 64;
  #pragma unroll
  for (int mt = 0; mt < 4; ++mt) {
    #pragma unroll
    for (int r = 0; r < 4; ++r) {
      int fr = fr0 + mt * 16 + (lane >> 4) * 4 + r;
      if (fr < NFRAMES) {
        int b = fr / KCF;
        #pragma unroll
        for (int nt = 0; nt < 4; ++nt) {
          int col = ncol0 + nt * 16 + (lane & 15);
          xg[(size_t)fr * GDIM + col] = acc[mt][nt][r] + embxg[(size_t)b * GDIM + col];
        }
      }
    }
  }
}

// ---------------- GRU: 1024 threads, split-K x4, weights RESIDENT in VGPRs ----------------
// Thread (g,u) owns cols {u,u+256,u+512} over k in [g*64,g*64+64): 48 float4 of wh
// loaded ONCE before the 13-step recurrence (static indexing via full unroll).
__global__ __launch_bounds__(1024) void k_gru(
    const float* __restrict__ xg, const float4* __restrict__ whT4,
    const float* __restrict__ bias, float* __restrict__ hs) {
  int c0 = blockIdx.x * GRU_CT;
  int tid = threadIdx.x;
  int g = tid >> 8;                      // K-split group: k in [g*64, g*64+64)
  int u = tid & 255;                     // unit
  __shared__ __align__(16) float h[GRU_CT][HDIM];        // 5 KB
  __shared__ float part[3][3][GRU_CT][HDIM];             // [group-1][gate][c][u] 45 KB
  for (int i = tid; i < GRU_CT * HDIM; i += 1024) (&h[0][0])[i] = 0.f;
  float b0 = bias[u], b1 = bias[u + 256], b2 = bias[u + 512];

  // ---- preload this thread's weight slice: 16 k-quads x 3 cols ----
  float4 W[16][3];
  {
    const float4* wp = whT4 + (size_t)(g * 16) * GDIM + u;
    #pragma unroll
    for (int i = 0; i < 16; ++i) {
      W[i][0] = wp[0];
      W[i][1] = wp[256];
      W[i][2] = wp[512];
      wp += GDIM;
    }
  }
  int kbase = g * 64;
  __syncthreads();

  for (int t = 0; t < NFR; ++t) {
    float a0[GRU_CT], a1[GRU_CT], a2[GRU_CT];
    #pragma unroll
    for (int c = 0; c < GRU_CT; ++c) { a0[c] = 0.f; a1[c] = 0.f; a2[c] = 0.f; }
    #pragma unroll
    for (int i = 0; i < 16; ++i) {
      float4 w0 = W[i][0], w1 = W[i][1], w2 = W[i][2];
      int k = kbase + i * 4;
      #pragma unroll
      for (int c = 0; c < GRU_CT; ++c) {
        float4 hv = *(const float4*)&h[c][k];     // broadcast read within group
        a0[c] = fmaf(hv.x, w0.x, a0[c]); a1[c] = fmaf(hv.x, w1.x, a1[c]); a2[c] = fmaf(hv.x, w2.x, a2[c]);
        a0[c] = fmaf(hv.y, w0.y, a0[c]); a1[c] = fmaf(hv.y, w1.y, a1[c]); a2[c] = fmaf(hv.y, w2.y, a2[c]);
        a0[c] = fmaf(hv.z, w0.z, a0[c]); a1[c] = fmaf(hv.z, w1.z, a1[c]); a2[c] = fmaf(hv.z, w2.z, a2[c]);
        a0[c] = fmaf(hv.w, w0.w, a0[c]); a1[c] = fmaf(hv.w, w1.w, a1[c]); a2[c] = fmaf(hv.w, w2.w, a2[c]);
      }
    }
    if (g > 0) {
      #pragma unroll
      for (int c = 0; c < GRU_CT; ++c) {
        part[g - 1][0][c][u] = a0[c];
        part[g - 1][1][c][u] = a1[c];
        part[g - 1][2][c][u] = a2[c];
      }
    }
    __syncthreads();      // partials visible; all GEMM reads of h done
    if (g == 0) {
      #pragma unroll
      for (int c = 0; c < GRU_CT; ++c) {
        int cb = c0 + c;
        if (cb < NCHUNKS) {
          const float* xgt = xg + (size_t)(cb * NFR + t) * GDIM;
          float g0 = a0[c] + part[0][0][c][u] + part[1][0][c][u] + part[2][0][c][u] + b0 + xgt[u];
          float g1 = a1[c] + part[0][1][c][u] + part[1][1][c][u] + part[2][1][c][u] + b1 + xgt[u + 256];
          float g2 = a2[c] + part[0][2][c][u] + part[1][2][c][u] + part[2][2][c][u] + b2;
          float z = 1.f / (1.f + expf(-g0));
          float r = 1.f / (1.f + expf(-g1));
          float n = tanhf(xgt[u + 512] + r * g2);
          float hn = (1.f - z) * n + z * h[c][u];
          h[c][u] = hn;   // unique (c,u): safe
          hs[(size_t)(cb * NFR + t) * HDIM + u] = hn;
        }
      }
    }
    __syncthreads();      // h updated before next step's GEMM
  }
}

// ---------------- proj GEMM via MFMA: gb[fr][col] = hs@pw + pb, bf16 output ----------------
__global__ __launch_bounds__(256) void k_proj(
    const float* __restrict__ hs, const short* __restrict__ pwb_hi,
    const short* __restrict__ pwb_lo, const float* __restrict__ pb,
    unsigned short* __restrict__ gb) {
  int nb  = blockIdx.x % PJ_NB;
  int mb  = blockIdx.x / PJ_NB;
  int fr0 = mb * 64;
  int tid = threadIdx.x;
  int lane = tid & 63;
  int wv   = tid >> 6;

  __shared__ __align__(16) short lsA[2][64 * 40];
  __shared__ __align__(16) short lsB[2][256 * 40];

  f32x4 acc[4][4];
  #pragma unroll
  for (int i = 0; i < 4; ++i)
    #pragma unroll
    for (int j = 0; j < 4; ++j)
      acc[i][j] = (f32x4){0.f, 0.f, 0.f, 0.f};

  int lrow = lane & 15;
  int lk8  = (lane >> 4) * 8;

  for (int ks = 0; ks < PJ_KS; ++ks) {
    {
      int f = tid >> 2, q = tid & 3;
      int fr = fr0 + f;
      float v[8];
      if (fr < NFRAMES) {
        const float* src = hs + (size_t)fr * HDIM + ks * 32 + q * 8;
        float4 v0 = *(const float4*)src;
        float4 v1 = *(const float4*)(src + 4);
        v[0]=v0.x; v[1]=v0.y; v[2]=v0.z; v[3]=v0.w;
        v[4]=v1.x; v[5]=v1.y; v[6]=v1.z; v[7]=v1.w;
      } else {
        #pragma unroll
        for (int j = 0; j < 8; ++j) v[j] = 0.f;
      }
      short hi[8], lo[8];
      #pragma unroll
      for (int j = 0; j < 8; ++j) split_bf16(v[j], hi[j], lo[j]);
      int off = f * 40 + q * 8;
      *(bf16x8*)&lsA[0][off] = *(bf16x8*)hi;
      *(bf16x8*)&lsA[1][off] = *(bf16x8*)lo;
    }
    {
      const short* gh = pwb_hi + (((size_t)nb * PJ_KS + ks) * 256 + tid) * 32;
      const short* gl = pwb_lo + (((size_t)nb * PJ_KS + ks) * 256 + tid) * 32;
      int off = tid * 40;
      #pragma unroll
      for (int i = 0; i < 4; ++i) {
        *(bf16x8*)&lsB[0][off + 8 * i] = *(const bf16x8*)(gh + 8 * i);
        *(bf16x8*)&lsB[1][off + 8 * i] = *(const bf16x8*)(gl + 8 * i);
      }
    }
    __syncthreads();
    bf16x8 aH[4], aL[4], bH[4], bL[4];
    #pragma unroll
    for (int mt = 0; mt < 4; ++mt) {
      int off = (16 * mt + lrow) * 40 + lk8;
      aH[mt] = *(const bf16x8*)&lsA[0][off];
      aL[mt] = *(const bf16x8*)&lsA[1][off];
    }
    #pragma unroll
    for (int nt = 0; nt < 4; ++nt) {
      int col = wv * 64 + nt * 16 + lrow;
      int off = col * 40 + lk8;
      bH[nt] = *(const bf16x8*)&lsB[0][off];
      bL[nt] = *(const bf16x8*)&lsB[1][off];
    }
    #pragma unroll
    for (int mt = 0; mt < 4; ++mt)
      #pragma unroll
      for (int nt = 0; nt < 4; ++nt) {
        acc[mt][nt] = __builtin_amdgcn_mfma_f32_16x16x32_bf16(aH[mt], bH[nt], acc[mt][nt], 0, 0, 0);
        acc[mt][nt] = __builtin_amdgcn_mfma_f32_16x16x32_bf16(aH[mt], bL[nt], acc[mt][nt], 0, 0, 0);
        acc[mt][nt] = __builtin_amdgcn_mfma_f32_16x16x32_bf16(aL[mt], bH[nt], acc[mt][nt], 0, 0, 0);
      }
    __syncthreads();
  }

  int ncol0 = nb * 256 + wv * 64;
  float pbv[4];
  int cols[4];
  #pragma unroll
  for (int nt = 0; nt < 4; ++nt) {
    cols[nt] = ncol0 + nt * 16 + (lane & 15);
    pbv[nt] = (cols[nt] < PDIM) ? pb[cols[nt]] : 0.f;
  }
  #pragma unroll
  for (int mt = 0; mt < 4; ++mt) {
    #pragma unroll
    for (int r = 0; r < 4; ++r) {
      int fr = fr0 + mt * 16 + (lane >> 4) * 4 + r;
      if (fr < NFRAMES) {
        #pragma unroll
        for (int nt = 0; nt < 4; ++nt) {
          if (cols[nt] < PDIM)
            gb[(size_t)fr * PDIM + cols[nt]] = f2bf(acc[mt][nt][r] + pbv[nt]);
        }
      }
    }
  }
}

// ---------------- inverse: modulate + tangle + 512-pt iFFT, 2 frames/block ----------------
__global__ void k_istft(unsigned* __restrict__ spec, const unsigned short* __restrict__ gb,
                        const float* __restrict__ win, const float* __restrict__ wsinv,
                        const float* __restrict__ gtwc, const float* __restrict__ gtws) {
  int fr0 = blockIdx.x * 2;
  int tid = threadIdx.x;
  __shared__ float sre[2][NFREQ], sim[2][NFREQ];   // 8.2 KB
  __shared__ float re[2][512], im[2][512];         // 8 KB
  __shared__ float twc[512], tws[512];             // 4 KB
  for (int i = tid; i < 512; i += 256) { twc[i] = gtwc[i]; tws[i] = gtws[i]; }
  for (int i = tid; i < 2 * NFREQ; i += 256) {
    int q = (i >= NFREQ) ? 1 : 0;
    int f = i - q * NFREQ;
    int fr = fr0 + q;
    unsigned pv = spec[(size_t)fr * (FR_STRIDE / 2) + f];
    float r  = bf2f((unsigned short)(pv & 0xFFFFu));
    float iv = bf2f((unsigned short)(pv >> 16));
    float mag = sqrtf(r * r + iv * iv);
    const unsigned short* gbrow = gb + (size_t)fr * PDIM;
    float gamma = bf2f(gbrow[f]);
    float beta  = bf2f(gbrow[NFREQ + f]);
    float mm = gamma * mag + beta;
    float nr, ni;
    if (mag > 0.f) {
      float s = mm / mag;
      nr = r * s; ni = iv * s;
    } else {
      nr = mm; ni = 0.f;   // angle(0)=0
    }
    sre[q][f] = nr;
    sim[q][f] = (f == 0 || f == NFREQ - 1) ? 0.f : ni;
  }
  __syncthreads();
  for (int i = tid; i < 1024; i += 256) {
    int q = i >> 9, n = i & 511;
    int k = (int)(__brev((unsigned)n) >> 23);   // Z'[k] goes to slot n
    float Xr = sre[q][k],       Xi = sim[q][k];
    float Mr = sre[q][512 - k], Mi = -sim[q][512 - k];   // conj(X[512-k])
    float xer = 0.5f * (Xr + Mr), xei = 0.5f * (Xi + Mi);
    float dr  = 0.5f * (Xr - Mr), di  = 0.5f * (Xi - Mi);
    float c = twc[k], s = tws[k];               // e^{+2pi i k/1024} = (c, +s)
    float xor_ = c * dr - s * di;
    float xoi  = c * di + s * dr;
    re[q][n] = xer - xoi;                       // Z' = Xe + i*Xo
    im[q][n] = xei + xor_;
  }
  __syncthreads();
  fft512x2(re, im, twc, tws, tid, +1.f);
  for (int i = tid; i < 1024; i += 256) {
    int q = i >> 9, n = i & 511;
    int fr = fr0 + q;
    int t = fr % NFR;
    int ia = 2 * n, ib = 2 * n + 1;
    float ya = re[q][n] * (1.0f / 512.0f) * win[ia] * wsinv[t * HOP_SZ + ia];
    float yb = im[q][n] * (1.0f / 512.0f) * win[ib] * wsinv[t * HOP_SZ + ib];
    unsigned* sp = spec + (size_t)fr * (FR_STRIDE / 2);
    sp[n] = (((unsigned)f2bf(yb)) << 16) | (unsigned)f2bf(ya);
  }
}

// ---------------- deterministic gather overlap-add (bf16 y) ----------------
__global__ void k_gather(const unsigned short* __restrict__ ybuf, float* __restrict__ out) {
  int gid = blockIdx.x * 256 + threadIdx.x;
  if (gid >= NB * T_LEN) return;
  int b = gid / T_LEN, pos = gid % T_LEN;
  float acc = 0.f;
  int k_hi = min(NK - 1, pos / STRIDESZ);
  int k_lo = (pos >= CHUNKSZ) ? ((pos - (CHUNKSZ - 1) + (STRIDESZ - 1)) / STRIDESZ) : 0;
  for (int k = k_lo; k <= k_hi; ++k) {
    int pc = pos - k * STRIDESZ;
    int t1 = min(NFR - 1, pc >> 8);
    int t0 = (pc > NFFT_SZ - 1) ? ((pc - 768) >> 8) : 0;
    int frbase = (b * NK + k) * NFR;
    for (int tt = t0; tt <= t1; ++tt) {
      acc += bf2f(ybuf[(size_t)(frbase + tt) * FR_STRIDE + (pc - tt * HOP_SZ)]);
    }
  }
  out[gid] = acc;
}

// ---------------- launch ----------------
extern "C" void kernel_launch(void* const* d_in, const int* in_sizes, int n_in,
                              void* d_out, int out_size, void* d_ws, size_t ws_size,
                              hipStream_t stream) {
  const float* audio     = (const float*)d_in[0];
  const float* emb_table = (const float*)d_in[1];
  const float* gru_wx    = (const float*)d_in[2];
  const float* gru_wh    = (const float*)d_in[3];
  const float* gru_b     = (const float*)d_in[4];
  const float* proj_w    = (const float*)d_in[5];
  const float* proj_b    = (const float*)d_in[6];
  const int*   effect_id = (const int*)d_in[7];
  float* out = (float*)d_out;

  char* base = (char*)d_ws;
  size_t off = 0;
  auto alloc = [&](size_t bytes) { char* p = base + off; off = (off + bytes + 255) & ~(size_t)255; return p; };
  unsigned* spec   = (unsigned*)alloc((size_t)NFRAMES * FR_STRIDE * 2);     // 33.5 MB (bf16 pairs)
  float*    xg     = (float*)   alloc((size_t)NFRAMES * GDIM * 4);          // 50.2 MB
  float*    hs     = (float*)   alloc((size_t)NFRAMES * HDIM * 4);          // 16.7 MB
  float*    win    = (float*)   alloc(NFFT_SZ * 4);
  float*    wsinv  = (float*)   alloc(CHUNKSZ * 4);
  float*    twc    = (float*)   alloc(512 * 4);
  float*    tws    = (float*)   alloc(512 * 4);
  float*    embxg  = (float*)   alloc(NB * GDIM * 4);
  short*    wxb_hi = (short*)   alloc((size_t)XG_NB * XG_KS * 256 * 32 * 2);
  short*    wxb_lo = (short*)   alloc((size_t)XG_NB * XG_KS * 256 * 32 * 2);
  short*    pwb_hi = (short*)   alloc((size_t)PJ_NB * PJ_KS * 256 * 32 * 2);
  short*    pwb_lo = (short*)   alloc((size_t)PJ_NB * PJ_KS * 256 * 32 * 2);
  float4*   whT4   = (float4*)  alloc((size_t)64 * GDIM * 16);              // 786 KB
  unsigned short* gb = (unsigned short*)xg;            // reuse xg region after k_gru

  k_tables  <<<1, 256, 0, stream>>>(win, wsinv, twc, tws);
  k_embxg   <<<NB, 256, 0, stream>>>(emb_table, effect_id, gru_wx, embxg);
  k_prep    <<<(XG_NB * XG_KS * 256 + 255) / 256, 256, 0, stream>>>(gru_wx, wxb_hi, wxb_lo);
  k_prep_wht<<<(64 * GDIM + 255) / 256, 256, 0, stream>>>(gru_wh, whT4);
  k_prep_pw <<<(PJ_NB * PJ_KS * 256 + 255) / 256, 256, 0, stream>>>(proj_w, pwb_hi, pwb_lo);
  k_stft    <<<NFRAMES / 2, 256, 0, stream>>>(audio, win, twc, tws, spec);
  k_xg      <<<256 * XG_NB, 256, 0, stream>>>(spec, embxg, wxb_hi, wxb_lo, xg);
  k_gru     <<<(NCHUNKS + GRU_CT - 1) / GRU_CT, 1024, 0, stream>>>(xg, whT4, gru_b, hs);
  k_proj    <<<256 * PJ_NB, 256, 0, stream>>>(hs, pwb_hi, pwb_lo, proj_b, gb);
  k_istft   <<<NFRAMES / 2, 256, 0, stream>>>(spec, gb, win, wsinv, twc, tws);
  k_gather  <<<(NB * T_LEN + 255) / 256, 256, 0, stream>>>((const unsigned short*)spec, out);
}

// Round 18
// 501.746 us; speedup vs baseline: 1.4608x; 1.4608x over previous
//
#include <hip/hip_runtime.h>
#include <math.h>

#define T_LEN    480000
#define NB       8
#define NK       157      // chunks per batch
#define CHUNKSZ  4096
#define STRIDESZ 3072
#define NFFT_SZ  1024
#define HOP_SZ   256
#define NFREQ    513
#define NFR      13       // frames per chunk
#define HDIM     256
#define EDIM     128
#define GDIM     768      // 3*HDIM
#define PDIM     1026     // 2*NFREQ
#define FR_STRIDE 1026    // bf16 shorts per frame slot in spec buffer (513 uints)
#define NFRAMES  (NB*NK*NFR)   // 16328
#define NCHUNKS  (NB*NK)       // 1256
#define KCF      2041          // NK*NFR, frames per batch

// xg-GEMM tiling
#define XG_KS    17            // K-steps of 32 (K padded 516 -> 544)
#define XG_NB    3             // N blocks of 256 (768 total)
// proj-GEMM tiling
#define PJ_KS    8             // K = 256
#define PJ_NB    5             // N blocks of 256 (1026 -> 1280 padded)
// GRU: 1024 threads (16 waves), split-K x4 (PROVEN round-16 version)
#define GRU_CT   5

#define TWO_PI_D 6.283185307179586

typedef short bf16x8 __attribute__((ext_vector_type(8)));
typedef float f32x4  __attribute__((ext_vector_type(4)));

__device__ __forceinline__ void split_bf16(float v, short& hi, short& lo) {
  unsigned u = __float_as_uint(v);
  hi = (short)(u >> 16);
  float fh = __uint_as_float(u & 0xFFFF0000u);
  float res = v - fh;
  lo = (short)(__float_as_uint(res) >> 16);
}

__device__ __forceinline__ unsigned short f2bf(float v) {   // round-to-nearest-even
  unsigned u = __float_as_uint(v);
  u += 0x7FFFu + ((u >> 16) & 1u);
  return (unsigned short)(u >> 16);
}
__device__ __forceinline__ float bf2f(unsigned short b) {
  return __uint_as_float(((unsigned)b) << 16);
}

// ---------------- 512-pt complex FFT x 2 frames, fused stage pairs ----------------
__device__ __forceinline__ void fft512x2(float (*re)[512], float (*im)[512],
                                         const float* twc, const float* tws,
                                         int tid, float dir) {
  int q = tid >> 7;        // frame
  int j = tid & 127;       // quad id (128 quads per frame)
  #pragma unroll
  for (int s = 1; s <= 7; s += 2) {
    int half = 1 << (s - 1);            // 1,4,16,64
    int p   = j & (half - 1);
    int grp = j >> (s - 1);
    int i0  = grp * 4 * half + p;
    int i1  = i0 + half;
    int i2  = i0 + 2 * half;
    int i3  = i0 + 3 * half;
    float r0 = re[q][i0], q0 = im[q][i0], r1 = re[q][i1], q1 = im[q][i1];
    float r2 = re[q][i2], q2 = im[q][i2], r3 = re[q][i3], q3 = im[q][i3];
    int qa = p << (10 - s);
    float ca = twc[qa], sa = dir * tws[qa];
    float tr = ca * r1 - sa * q1, ti = ca * q1 + sa * r1;
    float u0r = r0 + tr, u0i = q0 + ti;
    float u1r = r0 - tr, u1i = q0 - ti;
    tr = ca * r3 - sa * q3; ti = ca * q3 + sa * r3;
    float u2r = r2 + tr, u2i = q2 + ti;
    float u3r = r2 - tr, u3i = q2 - ti;
    int qb = p << (9 - s);
    int qc = (p + half) << (9 - s);
    float cb = twc[qb], sb = dir * tws[qb];
    float cc = twc[qc], sc = dir * tws[qc];
    tr = cb * u2r - sb * u2i; ti = cb * u2i + sb * u2r;
    re[q][i0] = u0r + tr; im[q][i0] = u0i + ti;
    re[q][i2] = u0r - tr; im[q][i2] = u0i - ti;
    tr = cc * u3r - sc * u3i; ti = cc * u3i + sc * u3r;
    re[q][i1] = u1r + tr; im[q][i1] = u1i + ti;
    re[q][i3] = u1r - tr; im[q][i3] = u1i - ti;
    __syncthreads();
  }
  {
    int p = tid;           // 0..255
    int qd = p << 1;       // e^{-2pi i p/512}
    float c = twc[qd], sn = dir * tws[qd];
    #pragma unroll
    for (int f = 0; f < 2; ++f) {
      int i1 = p, i2 = p + 256;
      float r2 = re[f][i2], q2 = im[f][i2];
      float tr = c * r2 - sn * q2;
      float ti = c * q2 + sn * r2;
      float r1 = re[f][i1], q1 = im[f][i1];
      re[f][i2] = r1 - tr; im[f][i2] = q1 - ti;
      re[f][i1] = r1 + tr; im[f][i1] = q1 + ti;
    }
    __syncthreads();
  }
}

// ---------------- window + 1/wsum + twiddle tables (recomputed every call) ----------------
__global__ void k_tables(float* __restrict__ win, float* __restrict__ wsinv,
                         float* __restrict__ twc, float* __restrict__ tws) {
  int tid = threadIdx.x;
  for (int i = tid; i < NFFT_SZ; i += 256) {
    double w = 0.5 - 0.5 * cos((TWO_PI_D / (double)NFFT_SZ) * (double)i);
    win[i] = (float)w;
  }
  for (int i = tid; i < 512; i += 256) {
    double th = (TWO_PI_D / (double)NFFT_SZ) * (double)i;
    twc[i] = (float)cos(th);
    tws[i] = (float)sin(th);
  }
  for (int pc = tid; pc < CHUNKSZ; pc += 256) {
    int t1 = min(NFR - 1, pc >> 8);
    int t0 = (pc > NFFT_SZ - 1) ? ((pc - 768) >> 8) : 0;
    float ws = 0.f;
    for (int tt = t0; tt <= t1; ++tt) {
      int n = pc - tt * HOP_SZ;
      double w = 0.5 - 0.5 * cos((TWO_PI_D / (double)NFFT_SZ) * (double)n);
      float wf = (float)w;
      ws += wf * wf;
    }
    wsinv[pc] = 1.0f / fmaxf(ws, 1e-8f);
  }
}

// ---------------- one-time wx transpose+split into blocked bf16 hi/lo ----------------
__global__ void k_prep(const float* __restrict__ wx,
                       short* __restrict__ wxb_hi, short* __restrict__ wxb_lo) {
  int id = blockIdx.x * 256 + threadIdx.x;
  if (id >= XG_NB * XG_KS * 256) return;
  int nb  = id / (XG_KS * 256);
  int ks  = (id / 256) % XG_KS;
  int col = id % 256;
  int col_g = nb * 256 + col;
  size_t base = (size_t)id * 32;
  for (int j = 0; j < 32; ++j) {
    int k_g = ks * 32 + j;
    float v = wx[(size_t)k_g * GDIM + col_g];
    short hi, lo;
    split_bf16(v, hi, lo);
    wxb_hi[base + j] = hi;
    wxb_lo[base + j] = lo;
  }
}

// ---------------- wh transpose: whT4[k/4][col] = float4(wh[k..k+3][col]) ----------------
__global__ void k_prep_wht(const float* __restrict__ wh, float4* __restrict__ whT4) {
  int id = blockIdx.x * 256 + threadIdx.x;   // over 64*768 float4s
  if (id >= 64 * GDIM) return;
  int k4  = id / GDIM;
  int col = id % GDIM;
  whT4[id] = make_float4(wh[(size_t)(k4 * 4 + 0) * GDIM + col],
                         wh[(size_t)(k4 * 4 + 1) * GDIM + col],
                         wh[(size_t)(k4 * 4 + 2) * GDIM + col],
                         wh[(size_t)(k4 * 4 + 3) * GDIM + col]);
}

// ---------------- pw transpose+split: pwb[nb][ks][col][32] hi/lo ----------------
__global__ void k_prep_pw(const float* __restrict__ pw,
                          short* __restrict__ pwb_hi, short* __restrict__ pwb_lo) {
  int id = blockIdx.x * 256 + threadIdx.x;   // over 5*8*256
  if (id >= PJ_NB * PJ_KS * 256) return;
  int nb  = id / (PJ_KS * 256);
  int ks  = (id / 256) % PJ_KS;
  int col = id % 256;
  int col_g = nb * 256 + col;
  size_t base = (size_t)id * 32;
  for (int j = 0; j < 32; ++j) {
    int k_g = ks * 32 + j;
    float v = (col_g < PDIM) ? pw[(size_t)k_g * PDIM + col_g] : 0.f;
    short hi, lo;
    split_bf16(v, hi, lo);
    pwb_hi[base + j] = hi;
    pwb_lo[base + j] = lo;
  }
}

// ---------------- emb @ wx_emb precompute: embxg[b][col] ----------------
__global__ void k_embxg(const float* __restrict__ emb_table, const int* __restrict__ effect_id,
                        const float* __restrict__ wx, float* __restrict__ embxg) {
  int b = blockIdx.x;
  int tid = threadIdx.x;
  int e_id = effect_id[b];
  const float* ev = emb_table + (size_t)e_id * EDIM;
  #pragma unroll
  for (int j = 0; j < 3; ++j) {
    int col = tid + 256 * j;
    float acc = 0.f;
    #pragma unroll 4
    for (int e = 0; e < EDIM; ++e)
      acc += ev[e] * wx[(size_t)(NFREQ + e) * GDIM + col];
    embxg[(size_t)b * GDIM + col] = acc;
  }
}

// ---------------- forward STFT via real-split 512-pt FFT, 2 frames/block ----------------
__global__ void k_stft(const float* __restrict__ audio, const float* __restrict__ win,
                       const float* __restrict__ gtwc, const float* __restrict__ gtws,
                       unsigned* __restrict__ spec) {
  int fr0 = blockIdx.x * 2;
  int tid = threadIdx.x;
  __shared__ float xin[2][NFFT_SZ];              // 8 KB
  __shared__ float re[2][512], im[2][512];       // 8 KB
  __shared__ float twc[512], tws[512];           // 4 KB
  for (int i = tid; i < 512; i += 256) { twc[i] = gtwc[i]; tws[i] = gtws[i]; }
  for (int i = tid; i < 2 * NFFT_SZ; i += 256) {
    int q = i >> 10, ii = i & 1023;
    int fr = fr0 + q;
    int b   = fr / KCF;
    int rem = fr % KCF;
    int k = rem / NFR, t = rem % NFR;
    int pos = k * STRIDESZ + t * HOP_SZ + ii;
    float v = (pos < T_LEN) ? audio[b * T_LEN + pos] : 0.f;
    xin[q][ii] = v * win[ii];
  }
  __syncthreads();
  for (int i = tid; i < 1024; i += 256) {
    int q = i >> 9, n = i & 511;
    int rv = (int)(__brev((unsigned)n) >> 23);
    re[q][n] = xin[q][2 * rv];
    im[q][n] = xin[q][2 * rv + 1];
  }
  __syncthreads();
  fft512x2(re, im, twc, tws, tid, -1.f);
  for (int i = tid; i < 1024; i += 256) {
    int q = i >> 9, k = i & 511;
    int m = (512 - k) & 511;
    float zr = re[q][k],  zi = im[q][k];
    float mr = re[q][m],  mi = -im[q][m];        // conj(Z[m])
    float xer = 0.5f * (zr + mr), xei = 0.5f * (zi + mi);
    float dr  = 0.5f * (zr - mr), di  = 0.5f * (zi - mi);
    float xor_ = di, xoi = -dr;
    float c = twc[k], s = tws[k];
    float Xr = xer + c * xor_ + s * xoi;
    float Xi = xei + c * xoi - s * xor_;
    unsigned* sp = spec + (size_t)(fr0 + q) * (FR_STRIDE / 2);
    sp[k] = (((unsigned)f2bf(Xi)) << 16) | (unsigned)f2bf(Xr);
  }
  if (tid < 2) {
    int q = tid;
    float Xr = re[q][0] - im[q][0];
    unsigned* sp = spec + (size_t)(fr0 + q) * (FR_STRIDE / 2);
    sp[512] = (((unsigned)f2bf(0.f)) << 16) | (unsigned)f2bf(Xr);
  }
}

// ---------------- xg GEMM via MFMA bf16x3 split ----------------
__global__ __launch_bounds__(256) void k_xg(
    const unsigned* __restrict__ spec, const float* __restrict__ embxg,
    const short* __restrict__ wxb_hi, const short* __restrict__ wxb_lo,
    float* __restrict__ xg) {
  int nb  = blockIdx.x % XG_NB;
  int mb  = blockIdx.x / XG_NB;
  int fr0 = mb * 64;
  int tid = threadIdx.x;
  int lane = tid & 63;
  int wv   = tid >> 6;

  __shared__ __align__(16) short lsA[2][64 * 40];
  __shared__ __align__(16) short lsB[2][256 * 40];

  f32x4 acc[4][4];
  #pragma unroll
  for (int i = 0; i < 4; ++i)
    #pragma unroll
    for (int j = 0; j < 4; ++j)
      acc[i][j] = (f32x4){0.f, 0.f, 0.f, 0.f};

  int lrow = lane & 15;
  int lk8  = (lane >> 4) * 8;

  for (int ks = 0; ks < XG_KS; ++ks) {
    int k0 = ks * 32;
    {
      int f = tid >> 2, q = tid & 3;
      int fr = fr0 + f;
      short hi[8], lo[8];
      #pragma unroll
      for (int j = 0; j < 8; ++j) {
        int bg = k0 + q * 8 + j;
        float m = 0.f;
        if (fr < NFRAMES && bg <= 512) {
          unsigned pv = spec[(size_t)fr * (FR_STRIDE / 2) + bg];
          float rr = bf2f((unsigned short)(pv & 0xFFFFu));
          float ii = bf2f((unsigned short)(pv >> 16));
          m = sqrtf(rr * rr + ii * ii);
        }
        split_bf16(m, hi[j], lo[j]);
      }
      int off = f * 40 + q * 8;
      *(bf16x8*)&lsA[0][off] = *(bf16x8*)hi;
      *(bf16x8*)&lsA[1][off] = *(bf16x8*)lo;
    }
    {
      const short* gh = wxb_hi + (((size_t)nb * XG_KS + ks) * 256 + tid) * 32;
      const short* gl = wxb_lo + (((size_t)nb * XG_KS + ks) * 256 + tid) * 32;
      int off = tid * 40;
      #pragma unroll
      for (int i = 0; i < 4; ++i) {
        *(bf16x8*)&lsB[0][off + 8 * i] = *(const bf16x8*)(gh + 8 * i);
        *(bf16x8*)&lsB[1][off + 8 * i] = *(const bf16x8*)(gl + 8 * i);
      }
    }
    __syncthreads();
    bf16x8 aH[4], aL[4], bH[4], bL[4];
    #pragma unroll
    for (int mt = 0; mt < 4; ++mt) {
      int off = (16 * mt + lrow) * 40 + lk8;
      aH[mt] = *(const bf16x8*)&lsA[0][off];
      aL[mt] = *(const bf16x8*)&lsA[1][off];
    }
    #pragma unroll
    for (int nt = 0; nt < 4; ++nt) {
      int col = wv * 64 + nt * 16 + lrow;
      int off = col * 40 + lk8;
      bH[nt] = *(const bf16x8*)&lsB[0][off];
      bL[nt] = *(const bf16x8*)&lsB[1][off];
    }
    #pragma unroll
    for (int mt = 0; mt < 4; ++mt)
      #pragma unroll
      for (int nt = 0; nt < 4; ++nt) {
        acc[mt][nt] = __builtin_amdgcn_mfma_f32_16x16x32_bf16(aH[mt], bH[nt], acc[mt][nt], 0, 0, 0);
        acc[mt][nt] = __builtin_amdgcn_mfma_f32_16x16x32_bf16(aH[mt], bL[nt], acc[mt][nt], 0, 0, 0);
        acc[mt][nt] = __builtin_amdgcn_mfma_f32_16x16x32_bf16(aL[mt], bH[nt], acc[mt][nt], 0, 0, 0);
      }
    __syncthreads();
  }

  int ncol0 = nb * 256 + wv * 64;
  #pragma unroll
  for (int mt = 0; mt < 4; ++mt) {
    #pragma unroll
    for (int r = 0; r < 4; ++r) {
      int fr = fr0 + mt * 16 + (lane >> 4) * 4 + r;
      if (fr < NFRAMES) {
        int b = fr / KCF;
        #pragma unroll
        for (int nt = 0; nt < 4; ++nt) {
          int col = ncol0 + nt * 16 + (lane & 15);
          xg[(size_t)fr * GDIM + col] = acc[mt][nt][r] + embxg[(size_t)b * GDIM + col];
        }
      }
    }
  }
}

// ---------------- GRU: 1024 threads, split-K x4 (PROVEN round-16) ----------------
__global__ __launch_bounds__(1024) void k_gru(
    const float* __restrict__ xg, const float4* __restrict__ whT4,
    const float* __restrict__ bias, float* __restrict__ hs) {
  int c0 = blockIdx.x * GRU_CT;
  int tid = threadIdx.x;
  int g = tid >> 8;                      // K-split group: k in [g*64, g*64+64)
  int u = tid & 255;                     // unit
  __shared__ __align__(16) float h[GRU_CT][HDIM];        // 5 KB
  __shared__ float part[3][3][GRU_CT][HDIM];             // [group-1][gate][c][u] 45 KB
  for (int i = tid; i < GRU_CT * HDIM; i += 1024) (&h[0][0])[i] = 0.f;
  float b0 = bias[u], b1 = bias[u + 256], b2 = bias[u + 512];
  __syncthreads();
  for (int t = 0; t < NFR; ++t) {
    float a0[GRU_CT], a1[GRU_CT], a2[GRU_CT];
    #pragma unroll
    for (int c = 0; c < GRU_CT; ++c) { a0[c] = 0.f; a1[c] = 0.f; a2[c] = 0.f; }
    const float4* wp = whT4 + (size_t)(g * 16) * GDIM + u;
    int kbase = g * 64;
    #pragma unroll 2
    for (int kk = 0; kk < 64; kk += 4) {
      float4 w0 = wp[0];
      float4 w1 = wp[256];
      float4 w2 = wp[512];
      wp += GDIM;
      int k = kbase + kk;
      #pragma unroll
      for (int c = 0; c < GRU_CT; ++c) {
        float4 hv = *(const float4*)&h[c][k];     // broadcast read within group
        a0[c] = fmaf(hv.x, w0.x, a0[c]); a1[c] = fmaf(hv.x, w1.x, a1[c]); a2[c] = fmaf(hv.x, w2.x, a2[c]);
        a0[c] = fmaf(hv.y, w0.y, a0[c]); a1[c] = fmaf(hv.y, w1.y, a1[c]); a2[c] = fmaf(hv.y, w2.y, a2[c]);
        a0[c] = fmaf(hv.z, w0.z, a0[c]); a1[c] = fmaf(hv.z, w1.z, a1[c]); a2[c] = fmaf(hv.z, w2.z, a2[c]);
        a0[c] = fmaf(hv.w, w0.w, a0[c]); a1[c] = fmaf(hv.w, w1.w, a1[c]); a2[c] = fmaf(hv.w, w2.w, a2[c]);
      }
    }
    if (g > 0) {
      #pragma unroll
      for (int c = 0; c < GRU_CT; ++c) {
        part[g - 1][0][c][u] = a0[c];
        part[g - 1][1][c][u] = a1[c];
        part[g - 1][2][c][u] = a2[c];
      }
    }
    __syncthreads();      // partials visible; all GEMM reads of h done
    if (g == 0) {
      #pragma unroll
      for (int c = 0; c < GRU_CT; ++c) {
        int cb = c0 + c;
        if (cb < NCHUNKS) {
          const float* xgt = xg + (size_t)(cb * NFR + t) * GDIM;
          float g0 = a0[c] + part[0][0][c][u] + part[1][0][c][u] + part[2][0][c][u] + b0 + xgt[u];
          float g1 = a1[c] + part[0][1][c][u] + part[1][1][c][u] + part[2][1][c][u] + b1 + xgt[u + 256];
          float g2 = a2[c] + part[0][2][c][u] + part[1][2][c][u] + part[2][2][c][u] + b2;
          float z = 1.f / (1.f + expf(-g0));
          float r = 1.f / (1.f + expf(-g1));
          float n = tanhf(xgt[u + 512] + r * g2);
          float hn = (1.f - z) * n + z * h[c][u];
          h[c][u] = hn;   // unique (c,u): safe
          hs[(size_t)(cb * NFR + t) * HDIM + u] = hn;
        }
      }
    }
    __syncthreads();      // h updated before next step's GEMM
  }
}

// ---------------- proj GEMM via MFMA: gb[fr][col] = hs@pw + pb, bf16 output ----------------
__global__ __launch_bounds__(256) void k_proj(
    const float* __restrict__ hs, const short* __restrict__ pwb_hi,
    const short* __restrict__ pwb_lo, const float* __restrict__ pb,
    unsigned short* __restrict__ gb) {
  int nb  = blockIdx.x % PJ_NB;
  int mb  = blockIdx.x / PJ_NB;
  int fr0 = mb * 64;
  int tid = threadIdx.x;
  int lane = tid & 63;
  int wv   = tid >> 6;

  __shared__ __align__(16) short lsA[2][64 * 40];
  __shared__ __align__(16) short lsB[2][256 * 40];

  f32x4 acc[4][4];
  #pragma unroll
  for (int i = 0; i < 4; ++i)
    #pragma unroll
    for (int j = 0; j < 4; ++j)
      acc[i][j] = (f32x4){0.f, 0.f, 0.f, 0.f};

  int lrow = lane & 15;
  int lk8  = (lane >> 4) * 8;

  for (int ks = 0; ks < PJ_KS; ++ks) {
    {
      int f = tid >> 2, q = tid & 3;
      int fr = fr0 + f;
      float v[8];
      if (fr < NFRAMES) {
        const float* src = hs + (size_t)fr * HDIM + ks * 32 + q * 8;
        float4 v0 = *(const float4*)src;
        float4 v1 = *(const float4*)(src + 4);
        v[0]=v0.x; v[1]=v0.y; v[2]=v0.z; v[3]=v0.w;
        v[4]=v1.x; v[5]=v1.y; v[6]=v1.z; v[7]=v1.w;
      } else {
        #pragma unroll
        for (int j = 0; j < 8; ++j) v[j] = 0.f;
      }
      short hi[8], lo[8];
      #pragma unroll
      for (int j = 0; j < 8; ++j) split_bf16(v[j], hi[j], lo[j]);
      int off = f * 40 + q * 8;
      *(bf16x8*)&lsA[0][off] = *(bf16x8*)hi;
      *(bf16x8*)&lsA[1][off] = *(bf16x8*)lo;
    }
    {
      const short* gh = pwb_hi + (((size_t)nb * PJ_KS + ks) * 256 + tid) * 32;
      const short* gl = pwb_lo + (((size_t)nb * PJ_KS + ks) * 256 + tid) * 32;
      int off = tid * 40;
      #pragma unroll
      for (int i = 0; i < 4; ++i) {
        *(bf16x8*)&lsB[0][off + 8 * i] = *(const bf16x8*)(gh + 8 * i);
        *(bf16x8*)&lsB[1][off + 8 * i] = *(const bf16x8*)(gl + 8 * i);
      }
    }
    __syncthreads();
    bf16x8 aH[4], aL[4], bH[4], bL[4];
    #pragma unroll
    for (int mt = 0; mt < 4; ++mt) {
      int off = (16 * mt + lrow) * 40 + lk8;
      aH[mt] = *(const bf16x8*)&lsA[0][off];
      aL[mt] = *(const bf16x8*)&lsA[1][off];
    }
    #pragma unroll
    for (int nt = 0; nt < 4; ++nt) {
      int col = wv * 64 + nt * 16 + lrow;
      int off = col * 40 + lk8;
      bH[nt] = *(const bf16x8*)&lsB[0][off];
      bL[nt] = *(const bf16x8*)&lsB[1][off];
    }
    #pragma unroll
    for (int mt = 0; mt < 4; ++mt)
      #pragma unroll
      for (int nt = 0; nt < 4; ++nt) {
        acc[mt][nt] = __builtin_amdgcn_mfma_f32_16x16x32_bf16(aH[mt], bH[nt], acc[mt][nt], 0, 0, 0);
        acc[mt][nt] = __builtin_amdgcn_mfma_f32_16x16x32_bf16(aH[mt], bL[nt], acc[mt][nt], 0, 0, 0);
        acc[mt][nt] = __builtin_amdgcn_mfma_f32_16x16x32_bf16(aL[mt], bH[nt], acc[mt][nt], 0, 0, 0);
      }
    __syncthreads();
  }

  int ncol0 = nb * 256 + wv * 64;
  float pbv[4];
  int cols[4];
  #pragma unroll
  for (int nt = 0; nt < 4; ++nt) {
    cols[nt] = ncol0 + nt * 16 + (lane & 15);
    pbv[nt] = (cols[nt] < PDIM) ? pb[cols[nt]] : 0.f;
  }
  #pragma unroll
  for (int mt = 0; mt < 4; ++mt) {
    #pragma unroll
    for (int r = 0; r < 4; ++r) {
      int fr = fr0 + mt * 16 + (lane >> 4) * 4 + r;
      if (fr < NFRAMES) {
        #pragma unroll
        for (int nt = 0; nt < 4; ++nt) {
          if (cols[nt] < PDIM)
            gb[(size_t)fr * PDIM + cols[nt]] = f2bf(acc[mt][nt][r] + pbv[nt]);
        }
      }
    }
  }
}

// ---------------- inverse: modulate + tangle + 512-pt iFFT, 2 frames/block ----------------
__global__ void k_istft(unsigned* __restrict__ spec, const unsigned short* __restrict__ gb,
                        const float* __restrict__ win, const float* __restrict__ wsinv,
                        const float* __restrict__ gtwc, const float* __restrict__ gtws) {
  int fr0 = blockIdx.x * 2;
  int tid = threadIdx.x;
  __shared__ float sre[2][NFREQ], sim[2][NFREQ];   // 8.2 KB
  __shared__ float re[2][512], im[2][512];         // 8 KB
  __shared__ float twc[512], tws[512];             // 4 KB
  for (int i = tid; i < 512; i += 256) { twc[i] = gtwc[i]; tws[i] = gtws[i]; }
  for (int i = tid; i < 2 * NFREQ; i += 256) {
    int q = (i >= NFREQ) ? 1 : 0;
    int f = i - q * NFREQ;
    int fr = fr0 + q;
    unsigned pv = spec[(size_t)fr * (FR_STRIDE / 2) + f];
    float r  = bf2f((unsigned short)(pv & 0xFFFFu));
    float iv = bf2f((unsigned short)(pv >> 16));
    float mag = sqrtf(r * r + iv * iv);
    const unsigned short* gbrow = gb + (size_t)fr * PDIM;
    float gamma = bf2f(gbrow[f]);
    float beta  = bf2f(gbrow[NFREQ + f]);
    float mm = gamma * mag + beta;
    float nr, ni;
    if (mag > 0.f) {
      float s = mm / mag;
      nr = r * s; ni = iv * s;
    } else {
      nr = mm; ni = 0.f;   // angle(0)=0
    }
    sre[q][f] = nr;
    sim[q][f] = (f == 0 || f == NFREQ - 1) ? 0.f : ni;
  }
  __syncthreads();
  for (int i = tid; i < 1024; i += 256) {
    int q = i >> 9, n = i & 511;
    int k = (int)(__brev((unsigned)n) >> 23);   // Z'[k] goes to slot n
    float Xr = sre[q][k],       Xi = sim[q][k];
    float Mr = sre[q][512 - k], Mi = -sim[q][512 - k];   // conj(X[512-k])
    float xer = 0.5f * (Xr + Mr), xei = 0.5f * (Xi + Mi);
    float dr  = 0.5f * (Xr - Mr), di  = 0.5f * (Xi - Mi);
    float c = twc[k], s = tws[k];               // e^{+2pi i k/1024} = (c, +s)
    float xor_ = c * dr - s * di;
    float xoi  = c * di + s * dr;
    re[q][n] = xer - xoi;                       // Z' = Xe + i*Xo
    im[q][n] = xei + xor_;
  }
  __syncthreads();
  fft512x2(re, im, twc, tws, tid, +1.f);
  for (int i = tid; i < 1024; i += 256) {
    int q = i >> 9, n = i & 511;
    int fr = fr0 + q;
    int t = fr % NFR;
    int ia = 2 * n, ib = 2 * n + 1;
    float ya = re[q][n] * (1.0f / 512.0f) * win[ia] * wsinv[t * HOP_SZ + ia];
    float yb = im[q][n] * (1.0f / 512.0f) * win[ib] * wsinv[t * HOP_SZ + ib];
    unsigned* sp = spec + (size_t)fr * (FR_STRIDE / 2);
    sp[n] = (((unsigned)f2bf(yb)) << 16) | (unsigned)f2bf(ya);
  }
}

// ---------------- deterministic gather overlap-add (bf16 y) ----------------
__global__ void k_gather(const unsigned short* __restrict__ ybuf, float* __restrict__ out) {
  int gid = blockIdx.x * 256 + threadIdx.x;
  if (gid >= NB * T_LEN) return;
  int b = gid / T_LEN, pos = gid % T_LEN;
  float acc = 0.f;
  int k_hi = min(NK - 1, pos / STRIDESZ);
  int k_lo = (pos >= CHUNKSZ) ? ((pos - (CHUNKSZ - 1) + (STRIDESZ - 1)) / STRIDESZ) : 0;
  for (int k = k_lo; k <= k_hi; ++k) {
    int pc = pos - k * STRIDESZ;
    int t1 = min(NFR - 1, pc >> 8);
    int t0 = (pc > NFFT_SZ - 1) ? ((pc - 768) >> 8) : 0;
    int frbase = (b * NK + k) * NFR;
    for (int tt = t0; tt <= t1; ++tt) {
      acc += bf2f(ybuf[(size_t)(frbase + tt) * FR_STRIDE + (pc - tt * HOP_SZ)]);
    }
  }
  out[gid] = acc;
}

// ---------------- launch ----------------
extern "C" void kernel_launch(void* const* d_in, const int* in_sizes, int n_in,
                              void* d_out, int out_size, void* d_ws, size_t ws_size,
                              hipStream_t stream) {
  const float* audio     = (const float*)d_in[0];
  const float* emb_table = (const float*)d_in[1];
  const float* gru_wx    = (const float*)d_in[2];
  const float* gru_wh    = (const float*)d_in[3];
  const float* gru_b     = (const float*)d_in[4];
  const float* proj_w    = (const float*)d_in[5];
  const float* proj_b    = (const float*)d_in[6];
  const int*   effect_id = (const int*)d_in[7];
  float* out = (float*)d_out;

  char* base = (char*)d_ws;
  size_t off = 0;
  auto alloc = [&](size_t bytes) { char* p = base + off; off = (off + bytes + 255) & ~(size_t)255; return p; };
  unsigned* spec   = (unsigned*)alloc((size_t)NFRAMES * FR_STRIDE * 2);     // 33.5 MB (bf16 pairs)
  float*    xg     = (float*)   alloc((size_t)NFRAMES * GDIM * 4);          // 50.2 MB
  float*    hs     = (float*)   alloc((size_t)NFRAMES * HDIM * 4);          // 16.7 MB
  float*    win    = (float*)   alloc(NFFT_SZ * 4);
  float*    wsinv  = (float*)   alloc(CHUNKSZ * 4);
  float*    twc    = (float*)   alloc(512 * 4);
  float*    tws    = (float*)   alloc(512 * 4);
  float*    embxg  = (float*)   alloc(NB * GDIM * 4);
  short*    wxb_hi = (short*)   alloc((size_t)XG_NB * XG_KS * 256 * 32 * 2);
  short*    wxb_lo = (short*)   alloc((size_t)XG_NB * XG_KS * 256 * 32 * 2);
  short*    pwb_hi = (short*)   alloc((size_t)PJ_NB * PJ_KS * 256 * 32 * 2);
  short*    pwb_lo = (short*)   alloc((size_t)PJ_NB * PJ_KS * 256 * 32 * 2);
  float4*   whT4   = (float4*)  alloc((size_t)64 * GDIM * 16);              // 786 KB
  unsigned short* gb = (unsigned short*)xg;            // reuse xg region after k_gru

  k_tables  <<<1, 256, 0, stream>>>(win, wsinv, twc, tws);
  k_embxg   <<<NB, 256, 0, stream>>>(emb_table, effect_id, gru_wx, embxg);
  k_prep    <<<(XG_NB * XG_KS * 256 + 255) / 256, 256, 0, stream>>>(gru_wx, wxb_hi, wxb_lo);
  k_prep_wht<<<(64 * GDIM + 255) / 256, 256, 0, stream>>>(gru_wh, whT4);
  k_prep_pw <<<(PJ_NB * PJ_KS * 256 + 255) / 256, 256, 0, stream>>>(proj_w, pwb_hi, pwb_lo);
  k_stft    <<<NFRAMES / 2, 256, 0, stream>>>(audio, win, twc, tws, spec);
  k_xg      <<<256 * XG_NB, 256, 0, stream>>>(spec, embxg, wxb_hi, wxb_lo, xg);
  k_gru     <<<(NCHUNKS + GRU_CT - 1) / GRU_CT, 1024, 0, stream>>>(xg, whT4, gru_b, hs);
  k_proj    <<<256 * PJ_NB, 256, 0, stream>>>(hs, pwb_hi, pwb_lo, proj_b, gb);
  k_istft   <<<NFRAMES / 2, 256, 0, stream>>>(spec, gb, win, wsinv, twc, tws);
  k_gather  <<<(NB * T_LEN + 255) / 256, 256, 0, stream>>>((const unsigned short*)spec, out);
}